// Round 1
// baseline (126.505 us; speedup 1.0000x reference)
//
#include <hip/hip_runtime.h>

// Problem constants (from reference setup_inputs)
#define BB    2      // batch
#define CIN   64
#define NI    64     // Cout
#define HIN   48
#define WIN   48
#define HO    96
#define WO    96
#define PH    50     // padded input dim (1 halo each side)
#define EPSN  1e-10f
#define IN_EPS 1e-5f

// d_ws layout (floats):
//   [0, XP)              zero-padded x: [B][CIN][PH][PH]
//   [F_OFF, F_OFF+F_N)   folded interior weights F[i][c][16]  (idx py*8+px*4+a*2+b)
//   [R_OFF, R_OFF+R_N)   class reciprocals     R[i][c][16]  (idx cy*4+cx)
// total = 320000 + 65536 + 65536 floats = 1,804,288 bytes  (needs ws_size >= ~1.8MB)
#define XP_N  (BB*CIN*PH*PH)
#define F_OFF XP_N
#define F_N   (NI*CIN*16)
#define R_OFF (F_OFF + F_N)

// ---------------- prep: zero-padded x copy ----------------
__global__ void pad_x_kernel(const float* __restrict__ x, float* __restrict__ ws) {
    const int slice = blockIdx.x;                 // b*CIN + c
    const float* xs = x + (size_t)slice * (HIN * WIN);
    float* xd = ws + (size_t)slice * (PH * PH);
    for (int e = threadIdx.x; e < PH * PH; e += blockDim.x) {
        int r = e / PH, col = e - r * PH;
        int h = r - 1, w = col - 1;
        float v = 0.f;
        if ((unsigned)h < HIN && (unsigned)w < WIN) v = xs[h * WIN + w];
        xd[e] = v;
    }
}

// ---------------- prep: folded weights + class reciprocal table ----------------
// Tap sets per parity: even y -> kh in {1,3}; odd y -> kh in {0,2}
// (a=0 is the tap at the HIGHER input row of the 2-tap pair).
// Boundary classes: 0: y==0 -> {1}; 1: odd interior -> {0,2}; 2: even interior -> {1,3}; 3: y==95 -> {2}
__global__ void prep_w_kernel(const float* __restrict__ Wt, float* __restrict__ ws) {
    const int i = blockIdx.x;    // out channel
    const int c = threadIdx.x;   // in channel
    float w[16];
    const float* wp = Wt + ((size_t)c * NI + i) * 16;
#pragma unroll
    for (int j = 0; j < 16; ++j) w[j] = wp[j];

    float* F = ws + F_OFF + ((size_t)i * CIN + c) * 16;
    float* R = ws + R_OFF + ((size_t)i * CIN + c) * 16;

    const int KH[2][2] = {{1, 3}, {0, 2}};   // [parity][a]
#pragma unroll
    for (int py = 0; py < 2; ++py) {
#pragma unroll
        for (int px = 0; px < 2; ++px) {
            float den = 0.f;
#pragma unroll
            for (int a = 0; a < 2; ++a)
#pragma unroll
                for (int b = 0; b < 2; ++b) den += w[KH[py][a] * 4 + KH[px][b]];
            float r = 1.f / (den + EPSN);
#pragma unroll
            for (int a = 0; a < 2; ++a)
#pragma unroll
                for (int b = 0; b < 2; ++b)
                    F[py * 8 + px * 4 + a * 2 + b] = w[KH[py][a] * 4 + KH[px][b]] * r;
        }
    }

    const int THn[4] = {1, 2, 2, 1};
    const int THv[4][2] = {{1, 1}, {0, 2}, {1, 3}, {2, 2}};
#pragma unroll
    for (int cy = 0; cy < 4; ++cy) {
#pragma unroll
        for (int cx = 0; cx < 4; ++cx) {
            float den = 0.f;
            for (int a = 0; a < THn[cy]; ++a)
                for (int b = 0; b < THn[cx]; ++b) den += w[THv[cy][a] * 4 + THv[cx][b]];
            R[cy * 4 + cx] = 1.f / (den + EPSN);
        }
    }
}

// ---------------- main: conv + boundary fixup + bias + instance norm ----------------
__launch_bounds__(256)
__global__ void norm_convt_kernel(const float* __restrict__ ws,
                                  const float* __restrict__ Wt,
                                  const float* __restrict__ bias,
                                  float* __restrict__ out) {
    const int bi = blockIdx.x;
    const int b = bi >> 6, i = bi & 63;
    const int tid = threadIdx.x;
    const int ty = tid >> 4, tx = tid & 15;   // 16x16 tiles of 6x6 outputs

    __shared__ float sW[CIN * 16];    // raw W[:, i, :, :]
    __shared__ float sR[CIN * 16];    // class reciprocals R[i, :, :]
    __shared__ float sFix[384];       // corrected boundary pixel values (pre-bias)
    __shared__ float sRed[16];

    // stage raw weights + class reciprocals for the fixup phase
    for (int e = tid; e < CIN * 16; e += 256) {
        int c = e >> 4, j = e & 15;
        sW[e] = Wt[((size_t)c * NI + i) * 16 + j];
    }
    {
        const float* Rg = ws + R_OFF + (size_t)i * CIN * 16;
        for (int e = tid; e < CIN * 16; e += 256) sR[e] = Rg[e];
    }

    float acc[6][6];
#pragma unroll
    for (int r = 0; r < 6; ++r)
#pragma unroll
        for (int j = 0; j < 6; ++j) acc[r][j] = 0.f;

    const float* Fg = ws + F_OFF + (size_t)i * CIN * 16;   // uniform -> s_load expected
    const float* xb = ws + (size_t)b * CIN * PH * PH + (3 * ty) * PH + 3 * tx;

    for (int c = 0; c < CIN; ++c) {
        // 16 folded weights, block-uniform
        float g[16];
        const float* fp = Fg + c * 16;
#pragma unroll
        for (int j = 0; j < 16; ++j) g[j] = fp[j];

        // 5x5 input patch (padded -> no OOB checks)
        const float* xc = xb + c * (PH * PH);
        float xv[5][5];
#pragma unroll
        for (int rr = 0; rr < 5; ++rr)
#pragma unroll
            for (int cc = 0; cc < 5; ++cc) xv[rr][cc] = xc[rr * PH + cc];

#pragma unroll
        for (int r = 0; r < 6; ++r) {
            const int rhi = (r + 3) >> 1, rlo = rhi - 1, py = r & 1;
#pragma unroll
            for (int j = 0; j < 6; ++j) {
                const int chi = (j + 3) >> 1, clo = chi - 1, px = j & 1;
                const float* gg = &g[py * 8 + px * 4];
                acc[r][j] += xv[rhi][chi] * gg[0] + xv[rhi][clo] * gg[1]
                           + xv[rlo][chi] * gg[2] + xv[rlo][clo] * gg[3];
            }
        }
    }

    __syncthreads();   // sW/sR staged

    // ---- boundary fixup: recompute the 380 edge pixels with correct denominators ----
    const float* xb2 = ws + (size_t)b * CIN * PH * PH;
    for (int p = tid; p < 380; p += 256) {
        int y, x;
        if (p < 96)       { y = 0;            x = p; }
        else if (p < 192) { y = 95;           x = p - 96; }
        else if (p < 286) { y = p - 192 + 1;  x = 0; }
        else              { y = p - 286 + 1;  x = 95; }
        const int hA = (y + 1) >> 1, khA = (y & 1) ? 0 : 1, hB = hA - 1, khB = khA + 2;
        const int wA = (x + 1) >> 1, kwA = (x & 1) ? 0 : 1, wB = wA - 1, kwB = kwA + 2;
        const int cy = (y == 0) ? 0 : (y == 95) ? 3 : ((y & 1) ? 1 : 2);
        const int cx = (x == 0) ? 0 : (x == 95) ? 3 : ((x & 1) ? 1 : 2);
        const int cls = cy * 4 + cx;
        float v = 0.f;
        for (int c = 0; c < CIN; ++c) {
            const float* xc = xb2 + c * (PH * PH);
            const float* wc = &sW[c * 16];
            float num = xc[(hA + 1) * PH + wA + 1] * wc[khA * 4 + kwA]
                      + xc[(hA + 1) * PH + wB + 1] * wc[khA * 4 + kwB]
                      + xc[(hB + 1) * PH + wA + 1] * wc[khB * 4 + kwA]
                      + xc[(hB + 1) * PH + wB + 1] * wc[khB * 4 + kwB];
            v += num * sR[c * 16 + cls];
        }
        sFix[p] = v;
    }
    __syncthreads();

    // owners replace their boundary pixels
#pragma unroll
    for (int r = 0; r < 6; ++r) {
#pragma unroll
        for (int j = 0; j < 6; ++j) {
            const int y = 6 * ty + r, x = 6 * tx + j;
            if (y == 0)        acc[r][j] = sFix[x];
            else if (y == 95)  acc[r][j] = sFix[96 + x];
            else if (x == 0)   acc[r][j] = sFix[192 + y - 1];
            else if (x == 95)  acc[r][j] = sFix[286 + y - 1];
        }
    }

    // ---- bias + instance norm ----
    const float bv = bias[i];
    float s1 = 0.f, s2 = 0.f;
#pragma unroll
    for (int r = 0; r < 6; ++r)
#pragma unroll
        for (int j = 0; j < 6; ++j) {
            float v = acc[r][j] + bv;
            acc[r][j] = v;
            s1 += v;
            s2 += v * v;
        }

#pragma unroll
    for (int off = 32; off > 0; off >>= 1) {
        s1 += __shfl_down(s1, off, 64);
        s2 += __shfl_down(s2, off, 64);
    }
    const int wid = tid >> 6;
    if ((tid & 63) == 0) { sRed[wid] = s1; sRed[4 + wid] = s2; }
    __syncthreads();
    if (tid == 0) {
        float t1 = sRed[0] + sRed[1] + sRed[2] + sRed[3];
        float t2 = sRed[4] + sRed[5] + sRed[6] + sRed[7];
        float mean = t1 * (1.f / 9216.f);
        float var = t2 * (1.f / 9216.f) - mean * mean;
        sRed[8] = mean;
        sRed[9] = 1.f / sqrtf(var + IN_EPS);
    }
    __syncthreads();
    const float mean = sRed[8], inv = sRed[9];

    float* ob = out + (((size_t)(b * NI + i)) * HO + 6 * ty) * WO + 6 * tx;
#pragma unroll
    for (int r = 0; r < 6; ++r) {
#pragma unroll
        for (int jj = 0; jj < 3; ++jj) {
            float2 v;
            v.x = (acc[r][2 * jj]     - mean) * inv;
            v.y = (acc[r][2 * jj + 1] - mean) * inv;
            *(float2*)(ob + r * WO + 2 * jj) = v;
        }
    }
}

extern "C" void kernel_launch(void* const* d_in, const int* in_sizes, int n_in,
                              void* d_out, int out_size, void* d_ws, size_t ws_size,
                              hipStream_t stream) {
    const float* x    = (const float*)d_in[0];
    const float* Wt   = (const float*)d_in[1];
    const float* bias = (const float*)d_in[2];
    float* out = (float*)d_out;
    float* ws  = (float*)d_ws;   // needs ~1.81 MB

    pad_x_kernel<<<BB * CIN, 256, 0, stream>>>(x, ws);
    prep_w_kernel<<<NI, 64, 0, stream>>>(Wt, ws);
    norm_convt_kernel<<<BB * NI, 256, 0, stream>>>(ws, Wt, bias, out);
}

// Round 2
// 114.239 us; speedup vs baseline: 1.1074x; 1.1074x over previous
//
#include <hip/hip_runtime.h>

// Problem constants (from reference setup_inputs)
#define BB    2      // batch
#define CIN   64
#define NI    64     // Cout
#define HIN   48
#define WIN   48
#define HO    96
#define WO    96
#define PH    50     // padded input dim (1 halo each side)
#define EPSN  1e-10f
#define IN_EPS 1e-5f

// d_ws layout (floats):
//   [0, XP_N)            zero-padded x: [B][CIN][PH][PH]
//   [F_OFF, +F_N)        folded interior weights F[i][c][16]
//   [R_OFF, +F_N)        class reciprocals     R[i][c][16]
//   [P_OFF, ...)         partial images [CS][128][9216], then bpart [CS][128][384]
#define XP_N  (BB*CIN*PH*PH)      // 320000
#define F_OFF XP_N
#define F_N   (NI*CIN*16)         // 65536
#define R_OFF (F_OFF + F_N)
#define P_OFF (R_OFF + F_N)       // 451072 floats

// ---------------- fused prep: pad x (blocks 0..127) + fold weights (blocks 128..143) ----
__global__ __launch_bounds__(256) void prep_kernel(const float* __restrict__ x,
                                                   const float* __restrict__ Wt,
                                                   float* __restrict__ ws) {
    const int blk = blockIdx.x;
    if (blk < BB * CIN) {
        const float* xs = x + (size_t)blk * (HIN * WIN);
        float* xd = ws + (size_t)blk * (PH * PH);
        for (int e = threadIdx.x; e < PH * PH; e += 256) {
            int r = e / PH, col = e - r * PH;
            int h = r - 1, w = col - 1;
            float v = 0.f;
            if ((unsigned)h < HIN && (unsigned)w < WIN) v = xs[h * WIN + w];
            xd[e] = v;
        }
        return;
    }
    // weight folding: 4 out-channels per block, 64 threads each
    const int i = (blk - BB * CIN) * 4 + (threadIdx.x >> 6);
    const int c = threadIdx.x & 63;
    float w[16];
    const float* wp = Wt + ((size_t)c * NI + i) * 16;
#pragma unroll
    for (int j = 0; j < 16; ++j) w[j] = wp[j];

    float* F = ws + F_OFF + ((size_t)i * CIN + c) * 16;
    float* R = ws + R_OFF + ((size_t)i * CIN + c) * 16;

    const int KH[2][2] = {{1, 3}, {0, 2}};   // [parity][a]
#pragma unroll
    for (int py = 0; py < 2; ++py)
#pragma unroll
        for (int px = 0; px < 2; ++px) {
            float den = 0.f;
#pragma unroll
            for (int a = 0; a < 2; ++a)
#pragma unroll
                for (int b = 0; b < 2; ++b) den += w[KH[py][a] * 4 + KH[px][b]];
            float r = 1.f / (den + EPSN);
#pragma unroll
            for (int a = 0; a < 2; ++a)
#pragma unroll
                for (int b = 0; b < 2; ++b)
                    F[py * 8 + px * 4 + a * 2 + b] = w[KH[py][a] * 4 + KH[px][b]] * r;
        }

    const int THn[4] = {1, 2, 2, 1};
    const int THv[4][2] = {{1, 1}, {0, 2}, {1, 3}, {2, 2}};
#pragma unroll
    for (int cy = 0; cy < 4; ++cy)
#pragma unroll
        for (int cx = 0; cx < 4; ++cx) {
            float den = 0.f;
            for (int a = 0; a < THn[cy]; ++a)
                for (int b = 0; b < THn[cx]; ++b) den += w[THv[cy][a] * 4 + THv[cx][b]];
            R[cy * 4 + cx] = 1.f / (den + EPSN);
        }
}

// ---------------- conv partial: grid (128, CS); block handles 64/CS channels ----------
template <int CS>
__global__ __launch_bounds__(256) void conv_partial_kernel(
        const float* __restrict__ ws, const float* __restrict__ Wt,
        float* __restrict__ part,      // [CS][128][9216]
        float* __restrict__ bpart) {   // [CS][128][384]
    constexpr int NC = CIN / CS;
    const int bi = blockIdx.x, s = blockIdx.y;
    const int b = bi >> 6, i = bi & 63;
    const int c0 = s * NC;
    const int tid = threadIdx.x;
    const int ty = tid >> 4, tx = tid & 15;

    __shared__ float sW[NC * 16];   // raw W for this chunk
    __shared__ float sR[NC * 16];   // class reciprocals for this chunk

    for (int e = tid; e < NC * 16; e += 256) {
        int c = e >> 4, j = e & 15;
        sW[e] = Wt[(((size_t)(c0 + c)) * NI + i) * 16 + j];
        sR[e] = ws[R_OFF + ((size_t)i * CIN + c0 + c) * 16 + j];
    }

    float acc[6][6];
#pragma unroll
    for (int r = 0; r < 6; ++r)
#pragma unroll
        for (int j = 0; j < 6; ++j) acc[r][j] = 0.f;

    const float* Fg = ws + F_OFF + ((size_t)i * CIN + c0) * 16;  // block-uniform
    const float* xb = ws + ((size_t)b * CIN + c0) * (PH * PH) + (3 * ty) * PH + 3 * tx;

#pragma unroll 2
    for (int c = 0; c < NC; ++c) {
        float g[16];
        const float* fp = Fg + c * 16;
#pragma unroll
        for (int j = 0; j < 16; ++j) g[j] = fp[j];

        const float* xc = xb + c * (PH * PH);
        float xv[5][5];
#pragma unroll
        for (int rr = 0; rr < 5; ++rr)
#pragma unroll
            for (int cc = 0; cc < 5; ++cc) xv[rr][cc] = xc[rr * PH + cc];

#pragma unroll
        for (int r = 0; r < 6; ++r) {
            const int rhi = (r + 3) >> 1, rlo = rhi - 1, py = r & 1;
#pragma unroll
            for (int j = 0; j < 6; ++j) {
                const int chi = (j + 3) >> 1, clo = chi - 1, px = j & 1;
                const float* gg = &g[py * 8 + px * 4];
                acc[r][j] += xv[rhi][chi] * gg[0] + xv[rhi][clo] * gg[1]
                           + xv[rlo][chi] * gg[2] + xv[rlo][clo] * gg[3];
            }
        }
    }

    // write partial tile
    float* pp = part + ((size_t)s * (BB * NI) + bi) * (HO * WO) + (6 * ty) * WO + 6 * tx;
#pragma unroll
    for (int r = 0; r < 6; ++r)
#pragma unroll
        for (int jj = 0; jj < 3; ++jj) {
            float2 v;
            v.x = acc[r][2 * jj];
            v.y = acc[r][2 * jj + 1];
            *(float2*)(pp + r * WO + 2 * jj) = v;
        }

    __syncthreads();   // sW/sR staged by all threads

    // boundary partials for this chunk (380 edge pixels, correct denominators)
    const float* xb2 = ws + ((size_t)b * CIN + c0) * (PH * PH);
    float* bp = bpart + ((size_t)s * (BB * NI) + bi) * 384;
    for (int p = tid; p < 380; p += 256) {
        int y, x;
        if (p < 96)       { y = 0;            x = p; }
        else if (p < 192) { y = 95;           x = p - 96; }
        else if (p < 286) { y = p - 192 + 1;  x = 0; }
        else              { y = p - 286 + 1;  x = 95; }
        const int hA = (y + 1) >> 1, khA = (y & 1) ? 0 : 1, hB = hA - 1, khB = khA + 2;
        const int wA = (x + 1) >> 1, kwA = (x & 1) ? 0 : 1, wB = wA - 1, kwB = kwA + 2;
        const int cy = (y == 0) ? 0 : (y == 95) ? 3 : ((y & 1) ? 1 : 2);
        const int cx = (x == 0) ? 0 : (x == 95) ? 3 : ((x & 1) ? 1 : 2);
        const int cls = cy * 4 + cx;
        float v = 0.f;
        for (int c = 0; c < NC; ++c) {
            const float* xc = xb2 + c * (PH * PH);
            const float* wc = &sW[c * 16];
            float num = xc[(hA + 1) * PH + wA + 1] * wc[khA * 4 + kwA]
                      + xc[(hA + 1) * PH + wB + 1] * wc[khA * 4 + kwB]
                      + xc[(hB + 1) * PH + wA + 1] * wc[khB * 4 + kwA]
                      + xc[(hB + 1) * PH + wB + 1] * wc[khB * 4 + kwB];
            v += num * sR[c * 16 + cls];
        }
        bp[p] = v;
    }
}

// ---------------- norm: sum partials + boundary replace + bias + instance norm -------
template <int CS>
__global__ __launch_bounds__(256) void norm_kernel(
        const float* __restrict__ part, const float* __restrict__ bpart,
        const float* __restrict__ bias, float* __restrict__ out) {
    const int bi = blockIdx.x;
    const int i = bi & 63;
    const int tid = threadIdx.x;

    __shared__ float sFix[384];
    __shared__ float sRed[16];

    for (int e = tid; e < 380; e += 256) {
        float v = 0.f;
#pragma unroll
        for (int s = 0; s < CS; ++s)
            v += bpart[((size_t)s * (BB * NI) + bi) * 384 + e];
        sFix[e] = v;
    }
    __syncthreads();

    const float bv = bias[i];
    const size_t stride = (size_t)(BB * NI) * (HO * WO);
    const float* pb = part + (size_t)bi * (HO * WO);

    float v[36];
    float s1 = 0.f, s2 = 0.f;
#pragma unroll
    for (int k = 0; k < 36; ++k) {
        const int p = tid + (k << 8);
        float t = 0.f;
#pragma unroll
        for (int s = 0; s < CS; ++s) t += pb[s * stride + p];
        const int y = p / 96, x = p - y * 96;
        if (y == 0)        t = sFix[x];
        else if (y == 95)  t = sFix[96 + x];
        else if (x == 0)   t = sFix[192 + y - 1];
        else if (x == 95)  t = sFix[286 + y - 1];
        t += bv;
        v[k] = t;
        s1 += t;
        s2 += t * t;
    }

#pragma unroll
    for (int off = 32; off > 0; off >>= 1) {
        s1 += __shfl_down(s1, off, 64);
        s2 += __shfl_down(s2, off, 64);
    }
    const int wid = tid >> 6;
    if ((tid & 63) == 0) { sRed[wid] = s1; sRed[4 + wid] = s2; }
    __syncthreads();
    if (tid == 0) {
        float t1 = sRed[0] + sRed[1] + sRed[2] + sRed[3];
        float t2 = sRed[4] + sRed[5] + sRed[6] + sRed[7];
        float mean = t1 * (1.f / 9216.f);
        float var = t2 * (1.f / 9216.f) - mean * mean;
        sRed[8] = mean;
        sRed[9] = 1.f / sqrtf(var + IN_EPS);
    }
    __syncthreads();
    const float mean = sRed[8], inv = sRed[9];

    float* ob = out + (size_t)bi * (HO * WO);
#pragma unroll
    for (int k = 0; k < 36; ++k) ob[tid + (k << 8)] = (v[k] - mean) * inv;
}

extern "C" void kernel_launch(void* const* d_in, const int* in_sizes, int n_in,
                              void* d_out, int out_size, void* d_ws, size_t ws_size,
                              hipStream_t stream) {
    const float* x    = (const float*)d_in[0];
    const float* Wt   = (const float*)d_in[1];
    const float* bias = (const float*)d_in[2];
    float* out = (float*)d_out;
    float* ws  = (float*)d_ws;

    prep_kernel<<<BB * CIN + 16, 256, 0, stream>>>(x, Wt, ws);

    const size_t IMG = (size_t)HO * WO;                 // 9216
    const size_t NIMG = (size_t)BB * NI;                // 128
    auto need = [&](int cs) {
        return ((size_t)P_OFF + (size_t)cs * NIMG * (IMG + 384)) * 4;
    };

    if (ws_size >= need(8)) {
        float* part  = ws + P_OFF;
        float* bpart = part + 8 * NIMG * IMG;
        conv_partial_kernel<8><<<dim3(NIMG, 8), 256, 0, stream>>>(ws, Wt, part, bpart);
        norm_kernel<8><<<NIMG, 256, 0, stream>>>(part, bpart, bias, out);
    } else if (ws_size >= need(4)) {
        float* part  = ws + P_OFF;
        float* bpart = part + 4 * NIMG * IMG;
        conv_partial_kernel<4><<<dim3(NIMG, 4), 256, 0, stream>>>(ws, Wt, part, bpart);
        norm_kernel<4><<<NIMG, 256, 0, stream>>>(part, bpart, bias, out);
    } else if (ws_size >= need(2)) {
        float* part  = ws + P_OFF;
        float* bpart = part + 2 * NIMG * IMG;
        conv_partial_kernel<2><<<dim3(NIMG, 2), 256, 0, stream>>>(ws, Wt, part, bpart);
        norm_kernel<2><<<NIMG, 256, 0, stream>>>(part, bpart, bias, out);
    } else {
        // last resort: conv writes straight into d_out, normalize in place
        float* bpart = ws + P_OFF;
        conv_partial_kernel<1><<<dim3(NIMG, 1), 256, 0, stream>>>(ws, Wt, out, bpart);
        norm_kernel<1><<<NIMG, 256, 0, stream>>>(out, bpart, bias, out);
    }
}

// Round 3
// 105.298 us; speedup vs baseline: 1.2014x; 1.0849x over previous
//
#include <hip/hip_runtime.h>

// Problem constants (from reference setup_inputs)
#define BB    2
#define CIN   64
#define NI    64
#define HIN   48
#define WIN   48
#define HO    96
#define WO    96
#define EPSN  1e-10f
#define IN_EPS 1e-5f
#define IMG   (HO*WO)     // 9216
#define NIMG  (BB*NI)     // 128

// ---------------------------------------------------------------------------
// conv: grid (NIMG, CS). Block (bi, s) computes the full 96x96 image for
// out-channel i, batch b over channel chunk [s*NC, (s+1)*NC), including the
// boundary fixup for its chunk, and writes it to part[s][bi][IMG].
// Weight folding is done in-block (no prep kernel): interior pixels use
// F = W * 1/(sum of 4 taps + eps); the 380 boundary pixels are recomputed
// with per-class denominators.
// ---------------------------------------------------------------------------
template <int CS>
__global__ __launch_bounds__(256) void conv_kernel(
        const float* __restrict__ x, const float* __restrict__ Wt,
        float* __restrict__ part) {
    constexpr int NC = CIN / CS;
    const int bi = blockIdx.x, s = blockIdx.y;
    const int b = bi >> 6, i = bi & 63, c0 = s * NC;
    const int tid = threadIdx.x;
    const int ty = tid >> 4, tx = tid & 15;

    __shared__ __align__(16) float sF[NC * 16];  // folded interior weights
    __shared__ float sW[NC * 16];                // raw weights (boundary pass)
    __shared__ float sR[NC * 16];                // per-class reciprocals
    __shared__ float sFix[384];

    // ---- in-block weight fold: one entry per (c, j) ----
    for (int e = tid; e < NC * 16; e += 256) {
        const int c = e >> 4, j = e & 15;
        const float* wp = Wt + ((size_t)(c0 + c) * NI + i) * 16;
        // raw weight j (kh*4+kw layout)
        sW[e] = wp[j];
        // folded interior: j = py*8 + px*4 + a*2 + bb
        const int py = (j >> 3) & 1, px = (j >> 2) & 1, a = (j >> 1) & 1, bb = j & 1;
        const int kh = py ? (a ? 2 : 0) : (a ? 3 : 1);   // KH[py][a], KH={{1,3},{0,2}}
        const int kw = px ? (bb ? 2 : 0) : (bb ? 3 : 1);
        const int r0 = py ? 0 : 1, r1 = py ? 2 : 3;
        const int q0 = px ? 0 : 1, q1 = px ? 2 : 3;
        const float den = wp[r0 * 4 + q0] + wp[r0 * 4 + q1]
                        + wp[r1 * 4 + q0] + wp[r1 * 4 + q1];
        sF[e] = wp[kh * 4 + kw] / (den + EPSN);
        // class reciprocal: j = cy*4 + cx
        const int cy = j >> 2, cx = j & 3;
        const int THn[4] = {1, 2, 2, 1};
        const int THv[4][2] = {{1, 1}, {0, 2}, {1, 3}, {2, 2}};
        float den2 = 0.f;
        for (int aa = 0; aa < THn[cy]; ++aa)
            for (int bb2 = 0; bb2 < THn[cx]; ++bb2)
                den2 += wp[THv[cy][aa] * 4 + THv[cx][bb2]];
        sR[e] = 1.f / (den2 + EPSN);
    }
    __syncthreads();

    // ---- per-thread patch geometry (clamped + masked, replaces padding) ----
    int rowOff[5], colIdx[5];
    bool rOk[5], cOk[5];
#pragma unroll
    for (int rr = 0; rr < 5; ++rr) {
        const int r = 3 * ty + rr - 1;
        rOk[rr] = (unsigned)r < (unsigned)HIN;
        rowOff[rr] = (rOk[rr] ? r : 0) * WIN;
    }
#pragma unroll
    for (int cc = 0; cc < 5; ++cc) {
        const int cI = 3 * tx + cc - 1;
        cOk[cc] = (unsigned)cI < (unsigned)WIN;
        colIdx[cc] = cOk[cc] ? cI : 0;
    }

    float acc[6][6];
#pragma unroll
    for (int r = 0; r < 6; ++r)
#pragma unroll
        for (int j = 0; j < 6; ++j) acc[r][j] = 0.f;

    const float* xb = x + ((size_t)b * CIN + c0) * (HIN * WIN);

#pragma unroll 2
    for (int c = 0; c < NC; ++c) {
        float g[16];
        const float4* gf = (const float4*)&sF[c * 16];
#pragma unroll
        for (int q = 0; q < 4; ++q) {
            const float4 t = gf[q];
            g[4 * q] = t.x; g[4 * q + 1] = t.y; g[4 * q + 2] = t.z; g[4 * q + 3] = t.w;
        }

        const float* xc = xb + c * (HIN * WIN);
        float xv[5][5];
#pragma unroll
        for (int rr = 0; rr < 5; ++rr)
#pragma unroll
            for (int cc = 0; cc < 5; ++cc) {
                const float v = xc[rowOff[rr] + colIdx[cc]];
                xv[rr][cc] = (rOk[rr] & cOk[cc]) ? v : 0.f;
            }

#pragma unroll
        for (int r = 0; r < 6; ++r) {
            const int rhi = (r + 3) >> 1, rlo = rhi - 1, py = r & 1;
#pragma unroll
            for (int j = 0; j < 6; ++j) {
                const int chi = (j + 3) >> 1, clo = chi - 1, px = j & 1;
                const float* gg = &g[py * 8 + px * 4];
                acc[r][j] += xv[rhi][chi] * gg[0] + xv[rhi][clo] * gg[1]
                           + xv[rlo][chi] * gg[2] + xv[rlo][clo] * gg[3];
            }
        }
    }

    // ---- boundary fixup for this chunk (380 edge pixels) ----
    for (int p = tid; p < 380; p += 256) {
        int y, xo;
        if (p < 96)       { y = 0;            xo = p; }
        else if (p < 192) { y = 95;           xo = p - 96; }
        else if (p < 286) { y = p - 192 + 1;  xo = 0; }
        else              { y = p - 286 + 1;  xo = 95; }
        const int hA = (y + 1) >> 1, hB = hA - 1;
        const int khA = (y & 1) ? 0 : 1, khB = khA + 2;
        const int wA = (xo + 1) >> 1, wB = wA - 1;
        const int kwA = (xo & 1) ? 0 : 1, kwB = kwA + 2;
        const bool okA = hA < HIN, okB = hB >= 0;
        const bool okC = wA < WIN, okD = wB >= 0;
        const int hAc = okA ? hA : 0, hBc = okB ? hB : 0;
        const int wAc = okC ? wA : 0, wBc = okD ? wB : 0;
        const int cy = (y == 0) ? 0 : (y == 95) ? 3 : ((y & 1) ? 1 : 2);
        const int cx = (xo == 0) ? 0 : (xo == 95) ? 3 : ((xo & 1) ? 1 : 2);
        const int cls = cy * 4 + cx;
        float v = 0.f;
        for (int c = 0; c < NC; ++c) {
            const float* xc = xb + c * (HIN * WIN);
            const float* wc = &sW[c * 16];
            float num = 0.f;
            if (okA & okC) num += xc[hAc * WIN + wAc] * wc[khA * 4 + kwA];
            if (okA & okD) num += xc[hAc * WIN + wBc] * wc[khA * 4 + kwB];
            if (okB & okC) num += xc[hBc * WIN + wAc] * wc[khB * 4 + kwA];
            if (okB & okD) num += xc[hBc * WIN + wBc] * wc[khB * 4 + kwB];
            v += num * sR[c * 16 + cls];
        }
        sFix[p] = v;
    }
    __syncthreads();

    // owners replace their boundary pixels
#pragma unroll
    for (int r = 0; r < 6; ++r)
#pragma unroll
        for (int j = 0; j < 6; ++j) {
            const int y = 6 * ty + r, xo = 6 * tx + j;
            if (y == 0)        acc[r][j] = sFix[xo];
            else if (y == 95)  acc[r][j] = sFix[96 + xo];
            else if (xo == 0)  acc[r][j] = sFix[192 + y - 1];
            else if (xo == 95) acc[r][j] = sFix[286 + y - 1];
        }

    // write partial (fully corrected for this chunk)
    float* pp = part + ((size_t)s * NIMG + bi) * IMG + (6 * ty) * WO + 6 * tx;
#pragma unroll
    for (int r = 0; r < 6; ++r)
#pragma unroll
        for (int jj = 0; jj < 3; ++jj) {
            float2 v;
            v.x = acc[r][2 * jj];
            v.y = acc[r][2 * jj + 1];
            *(float2*)(pp + r * WO + 2 * jj) = v;
        }
}

// ---------------------------------------------------------------------------
// reduce_stats: grid (3, NIMG). Sums CS partials (float4), adds bias, writes
// summed image and per-slice (s1, s2).
// ---------------------------------------------------------------------------
template <int CS>
__global__ __launch_bounds__(256) void reduce_stats_kernel(
        const float* __restrict__ part, const float* __restrict__ bias,
        float* __restrict__ sumimg, float2* __restrict__ pairs) {
    const int slice = blockIdx.x, bi = blockIdx.y;
    const int tid = threadIdx.x;
    const float bv = bias[bi & 63];
    const float4* pb = (const float4*)part + (size_t)bi * (IMG / 4);
    const size_t stride4 = (size_t)NIMG * (IMG / 4);
    float4* sb = (float4*)sumimg + (size_t)bi * (IMG / 4);

    float s1 = 0.f, s2 = 0.f;
#pragma unroll
    for (int k = 0; k < 3; ++k) {
        const int idx = slice * 768 + k * 256 + tid;
        float4 t = pb[idx];
#pragma unroll
        for (int s = 1; s < CS; ++s) {
            const float4 q = pb[s * stride4 + idx];
            t.x += q.x; t.y += q.y; t.z += q.z; t.w += q.w;
        }
        t.x += bv; t.y += bv; t.z += bv; t.w += bv;
        sb[idx] = t;
        s1 += t.x + t.y + t.z + t.w;
        s2 += t.x * t.x + t.y * t.y + t.z * t.z + t.w * t.w;
    }

    __shared__ float red[8];
#pragma unroll
    for (int off = 32; off > 0; off >>= 1) {
        s1 += __shfl_down(s1, off, 64);
        s2 += __shfl_down(s2, off, 64);
    }
    if ((tid & 63) == 0) { red[tid >> 6] = s1; red[4 + (tid >> 6)] = s2; }
    __syncthreads();
    if (tid == 0)
        pairs[bi * 3 + slice] = make_float2(red[0] + red[1] + red[2] + red[3],
                                            red[4] + red[5] + red[6] + red[7]);
}

// ---------------------------------------------------------------------------
// normalize: grid (3, NIMG). mean/inv from the 3 slice pairs, then scale.
// ---------------------------------------------------------------------------
__global__ __launch_bounds__(256) void normalize_kernel(
        const float* __restrict__ sumimg, const float2* __restrict__ pairs,
        float* __restrict__ out) {
    const int slice = blockIdx.x, bi = blockIdx.y;
    const int tid = threadIdx.x;
    const float2 p0 = pairs[bi * 3 + 0], p1 = pairs[bi * 3 + 1], p2 = pairs[bi * 3 + 2];
    const float mean = (p0.x + p1.x + p2.x) * (1.f / 9216.f);
    const float m2   = (p0.y + p1.y + p2.y) * (1.f / 9216.f);
    const float inv  = rsqrtf(m2 - mean * mean + IN_EPS);
    const float4* sb = (const float4*)sumimg + (size_t)bi * (IMG / 4);
    float4* ob = (float4*)out + (size_t)bi * (IMG / 4);
#pragma unroll
    for (int k = 0; k < 3; ++k) {
        const int idx = slice * 768 + k * 256 + tid;
        float4 t = sb[idx];
        t.x = (t.x - mean) * inv; t.y = (t.y - mean) * inv;
        t.z = (t.z - mean) * inv; t.w = (t.w - mean) * inv;
        ob[idx] = t;
    }
}

extern "C" void kernel_launch(void* const* d_in, const int* in_sizes, int n_in,
                              void* d_out, int out_size, void* d_ws, size_t ws_size,
                              hipStream_t stream) {
    const float* x    = (const float*)d_in[0];
    const float* Wt   = (const float*)d_in[1];
    const float* bias = (const float*)d_in[2];
    float* out = (float*)d_out;
    float* ws  = (float*)d_ws;

    const size_t need4 = ((size_t)4 * NIMG * IMG + (size_t)NIMG * IMG + NIMG * 6) * 4;
    if (ws_size >= need4) {
        float* part   = ws;
        float* sumimg = ws + (size_t)4 * NIMG * IMG;
        float2* pairs = (float2*)(ws + (size_t)5 * NIMG * IMG);
        conv_kernel<4><<<dim3(NIMG, 4), 256, 0, stream>>>(x, Wt, part);
        reduce_stats_kernel<4><<<dim3(3, NIMG), 256, 0, stream>>>(part, bias, sumimg, pairs);
        normalize_kernel<<<dim3(3, NIMG), 256, 0, stream>>>(sumimg, pairs, out);
    } else {
        // fallback: conv writes the (correct, pre-bias) image straight to out,
        // stats + in-place normalize; needs only 3 KB of ws.
        float2* pairs = (float2*)ws;
        conv_kernel<1><<<dim3(NIMG, 1), 256, 0, stream>>>(x, Wt, out);
        reduce_stats_kernel<1><<<dim3(3, NIMG), 256, 0, stream>>>(out, bias, out, pairs);
        normalize_kernel<<<dim3(3, NIMG), 256, 0, stream>>>(out, pairs, out);
    }
}

// Round 4
// 96.678 us; speedup vs baseline: 1.3085x; 1.0892x over previous
//
#include <hip/hip_runtime.h>

// Problem constants (from reference setup_inputs)
#define BB    2
#define CIN   64
#define NI    64
#define HIN   48
#define WIN   48
#define HO    96
#define WO    96
#define EPSN  1e-10f
#define IN_EPS 1e-5f
#define IMG   (HO*WO)     // 9216
#define NIMG  (BB*NI)     // 128
#define PH    50          // padded rows: input row h -> padded row h+1, rows -1..48
#define PW    52          // padded cols (52 keeps strides 0 mod 4)
#define XPN   (BB*CIN*PH*PW)   // 332800 floats

// ---------------------------------------------------------------------------
// prep: zero-padded x copy. grid 256 = (slice, half); slice = b*CIN+c.
// ---------------------------------------------------------------------------
__global__ __launch_bounds__(256) void pad_kernel(const float* __restrict__ x,
                                                  float* __restrict__ xpad) {
    const int slice = blockIdx.x >> 1, half = blockIdx.x & 1;
    const float* xs = x + (size_t)slice * (HIN * WIN);
    float* xd = xpad + (size_t)slice * (PH * PW) + half * 25 * PW;
    for (int e = threadIdx.x; e < 25 * PW; e += 256) {
        const int rp = e / PW, pc = e - rp * PW;
        const int h = half * 25 + rp - 1, w = pc - 1;
        float v = 0.f;
        if ((unsigned)h < HIN && (unsigned)w < WIN) v = xs[h * WIN + w];
        xd[e] = v;
    }
}

// ---------------------------------------------------------------------------
// conv: grid (NIMG, CS). Block (bi, s) computes the full 96x96 image for
// out-channel i, batch b over channels [s*NC,(s+1)*NC), boundary-corrected,
// into part[s][bi][IMG]. Weight folding is in-block.
// ---------------------------------------------------------------------------
template <int CS>
__global__ __launch_bounds__(256) void conv_kernel(
        const float* __restrict__ xpad, const float* __restrict__ Wt,
        float* __restrict__ part) {
    constexpr int NC = CIN / CS;
    const int bi = blockIdx.x, s = blockIdx.y;
    const int b = bi >> 6, i = bi & 63, c0 = s * NC;
    const int tid = threadIdx.x;
    const int ty = tid >> 4, tx = tid & 15;

    __shared__ __align__(16) float sF[NC * 16];  // folded interior weights
    __shared__ float sW[NC * 16];                // raw weights (boundary pass)
    __shared__ float sR[NC * 16];                // per-class reciprocals
    __shared__ float sFix[384];

    // ---- in-block weight fold ----
    for (int e = tid; e < NC * 16; e += 256) {
        const int c = e >> 4, j = e & 15;
        const float* wp = Wt + ((size_t)(c0 + c) * NI + i) * 16;
        sW[e] = wp[j];
        // folded interior: j = py*8 + px*4 + a*2 + bb
        const int py = (j >> 3) & 1, px = (j >> 2) & 1, a = (j >> 1) & 1, bb = j & 1;
        const int kh = py ? (a ? 2 : 0) : (a ? 3 : 1);
        const int kw = px ? (bb ? 2 : 0) : (bb ? 3 : 1);
        const int r0 = py ? 0 : 1, r1 = py ? 2 : 3;
        const int q0 = px ? 0 : 1, q1 = px ? 2 : 3;
        const float den = wp[r0 * 4 + q0] + wp[r0 * 4 + q1]
                        + wp[r1 * 4 + q0] + wp[r1 * 4 + q1];
        sF[e] = wp[kh * 4 + kw] / (den + EPSN);
        // class reciprocal: j = cy*4 + cx
        const int cy = j >> 2, cx = j & 3;
        const int THn[4] = {1, 2, 2, 1};
        const int THv[4][2] = {{1, 1}, {0, 2}, {1, 3}, {2, 2}};
        float den2 = 0.f;
        for (int aa = 0; aa < THn[cy]; ++aa)
            for (int bb2 = 0; bb2 < THn[cx]; ++bb2)
                den2 += wp[THv[cy][aa] * 4 + THv[cx][bb2]];
        sR[e] = 1.f / (den2 + EPSN);
    }
    __syncthreads();

    float acc[6][6];
#pragma unroll
    for (int r = 0; r < 6; ++r)
#pragma unroll
        for (int j = 0; j < 6; ++j) acc[r][j] = 0.f;

    // patch base: padded rows 3ty.. (input rows 3ty-1..), padded cols 3tx..
    const float* xb = xpad + ((size_t)b * CIN + c0) * (PH * PW) + (3 * ty) * PW + 3 * tx;

#pragma unroll 2
    for (int c = 0; c < NC; ++c) {
        float g[16];
        const float4* gf = (const float4*)&sF[c * 16];
#pragma unroll
        for (int q = 0; q < 4; ++q) {
            const float4 t = gf[q];
            g[4 * q] = t.x; g[4 * q + 1] = t.y; g[4 * q + 2] = t.z; g[4 * q + 3] = t.w;
        }

        const float* xc = xb + c * (PH * PW);
        float xv[5][5];
#pragma unroll
        for (int rr = 0; rr < 5; ++rr)
#pragma unroll
            for (int cc = 0; cc < 5; ++cc) xv[rr][cc] = xc[rr * PW + cc];   // imm offsets

#pragma unroll
        for (int r = 0; r < 6; ++r) {
            const int rhi = (r + 3) >> 1, rlo = rhi - 1, py = r & 1;
#pragma unroll
            for (int j = 0; j < 6; ++j) {
                const int chi = (j + 3) >> 1, clo = chi - 1, px = j & 1;
                const float* gg = &g[py * 8 + px * 4];
                acc[r][j] += xv[rhi][chi] * gg[0] + xv[rhi][clo] * gg[1]
                           + xv[rlo][chi] * gg[2] + xv[rlo][clo] * gg[3];
            }
        }
    }

    // ---- boundary fixup for this chunk (padding zeros make invalid taps 0) ----
    const float* xb2 = xpad + ((size_t)b * CIN + c0) * (PH * PW);
    for (int p = tid; p < 380; p += 256) {
        int y, xo;
        if (p < 96)       { y = 0;            xo = p; }
        else if (p < 192) { y = 95;           xo = p - 96; }
        else if (p < 286) { y = p - 192 + 1;  xo = 0; }
        else              { y = p - 286 + 1;  xo = 95; }
        const int hA = (y + 1) >> 1, hB = hA - 1;
        const int khA = (y & 1) ? 0 : 1, khB = khA + 2;
        const int wA = (xo + 1) >> 1, wB = wA - 1;
        const int kwA = (xo & 1) ? 0 : 1, kwB = kwA + 2;
        const int cy = (y == 0) ? 0 : (y == 95) ? 3 : ((y & 1) ? 1 : 2);
        const int cx = (xo == 0) ? 0 : (xo == 95) ? 3 : ((xo & 1) ? 1 : 2);
        const int cls = cy * 4 + cx;
        const int rA = (hA + 1) * PW, rB = (hB + 1) * PW;
        float v = 0.f;
        for (int c = 0; c < NC; ++c) {
            const float* xc = xb2 + c * (PH * PW);
            const float* wc = &sW[c * 16];
            const float num = xc[rA + wA + 1] * wc[khA * 4 + kwA]
                            + xc[rA + wB + 1] * wc[khA * 4 + kwB]
                            + xc[rB + wA + 1] * wc[khB * 4 + kwA]
                            + xc[rB + wB + 1] * wc[khB * 4 + kwB];
            v += num * sR[c * 16 + cls];
        }
        sFix[p] = v;
    }
    __syncthreads();

    // owners replace their boundary pixels
#pragma unroll
    for (int r = 0; r < 6; ++r)
#pragma unroll
        for (int j = 0; j < 6; ++j) {
            const int y = 6 * ty + r, xo = 6 * tx + j;
            if (y == 0)        acc[r][j] = sFix[xo];
            else if (y == 95)  acc[r][j] = sFix[96 + xo];
            else if (xo == 0)  acc[r][j] = sFix[192 + y - 1];
            else if (xo == 95) acc[r][j] = sFix[286 + y - 1];
        }

    // write partial
    float* pp = part + ((size_t)s * NIMG + bi) * IMG + (6 * ty) * WO + 6 * tx;
#pragma unroll
    for (int r = 0; r < 6; ++r)
#pragma unroll
        for (int jj = 0; jj < 3; ++jj) {
            float2 v;
            v.x = acc[r][2 * jj];
            v.y = acc[r][2 * jj + 1];
            *(float2*)(pp + r * WO + 2 * jj) = v;
        }
}

// ---------------------------------------------------------------------------
// epilogue: grid NIMG x 768 threads (12 waves). Sum CS partials (float4),
// +bias, block-wide stats, normalize, write out. Safe in-place (part==out,
// CS==1): all reads precede the barrier, writes follow it.
// ---------------------------------------------------------------------------
template <int CS>
__global__ __launch_bounds__(768) void epilogue_kernel(
        const float* __restrict__ part, const float* __restrict__ bias,
        float* __restrict__ out) {
    const int bi = blockIdx.x;
    const int tid = threadIdx.x;
    const float bv = bias[bi & 63];
    const float4* pb = (const float4*)part + (size_t)bi * (IMG / 4);
    const size_t stride4 = (size_t)NIMG * (IMG / 4);

    float4 v[3];
    float s1 = 0.f, s2 = 0.f;
#pragma unroll
    for (int k = 0; k < 3; ++k) {
        const int idx = k * 768 + tid;
        float4 t = pb[idx];
#pragma unroll
        for (int s = 1; s < CS; ++s) {
            const float4 q = pb[s * stride4 + idx];
            t.x += q.x; t.y += q.y; t.z += q.z; t.w += q.w;
        }
        t.x += bv; t.y += bv; t.z += bv; t.w += bv;
        v[k] = t;
        s1 += t.x + t.y + t.z + t.w;
        s2 += t.x * t.x + t.y * t.y + t.z * t.z + t.w * t.w;
    }

    __shared__ float red[24];
    __shared__ float stat[2];
#pragma unroll
    for (int off = 32; off > 0; off >>= 1) {
        s1 += __shfl_down(s1, off, 64);
        s2 += __shfl_down(s2, off, 64);
    }
    const int w = tid >> 6;
    if ((tid & 63) == 0) { red[w] = s1; red[12 + w] = s2; }
    __syncthreads();
    if (tid == 0) {
        float t1 = 0.f, t2 = 0.f;
#pragma unroll
        for (int k = 0; k < 12; ++k) { t1 += red[k]; t2 += red[12 + k]; }
        const float mean = t1 * (1.f / 9216.f);
        const float m2 = t2 * (1.f / 9216.f);
        stat[0] = mean;
        stat[1] = rsqrtf(m2 - mean * mean + IN_EPS);
    }
    __syncthreads();
    const float mean = stat[0], inv = stat[1];

    float4* ob = (float4*)out + (size_t)bi * (IMG / 4);
#pragma unroll
    for (int k = 0; k < 3; ++k) {
        const int idx = k * 768 + tid;
        float4 t = v[k];
        t.x = (t.x - mean) * inv; t.y = (t.y - mean) * inv;
        t.z = (t.z - mean) * inv; t.w = (t.w - mean) * inv;
        ob[idx] = t;
    }
}

extern "C" void kernel_launch(void* const* d_in, const int* in_sizes, int n_in,
                              void* d_out, int out_size, void* d_ws, size_t ws_size,
                              hipStream_t stream) {
    const float* x    = (const float*)d_in[0];
    const float* Wt   = (const float*)d_in[1];
    const float* bias = (const float*)d_in[2];
    float* out = (float*)d_out;
    float* ws  = (float*)d_ws;

    float* xpad = ws;
    pad_kernel<<<BB * CIN * 2, 256, 0, stream>>>(x, xpad);

    const size_t need4 = ((size_t)XPN + (size_t)4 * NIMG * IMG) * 4;
    if (ws_size >= need4) {
        float* part = ws + XPN;
        conv_kernel<4><<<dim3(NIMG, 4), 256, 0, stream>>>(xpad, Wt, part);
        epilogue_kernel<4><<<NIMG, 768, 0, stream>>>(part, bias, out);
    } else {
        // fallback: conv writes the corrected pre-bias image straight to out,
        // epilogue normalizes in place. Needs only the xpad region of ws.
        conv_kernel<1><<<dim3(NIMG, 1), 256, 0, stream>>>(xpad, Wt, out);
        epilogue_kernel<1><<<NIMG, 768, 0, stream>>>(out, bias, out);
    }
}

// Round 5
// 89.879 us; speedup vs baseline: 1.4075x; 1.0757x over previous
//
#include <hip/hip_runtime.h>

// Problem constants (from reference setup_inputs)
#define BB    2
#define CIN   64
#define NI    64
#define HIN   48
#define WIN   48
#define HO    96
#define WO    96
#define EPSN  1e-10f
#define IN_EPS 1e-5f
#define IMG   (HO*WO)     // 9216
#define NIMG  (BB*NI)     // 128
// LDS tile: padded rows 0..49 (input row h -> padded h+1), cols: input col w -> w+4
#define LPH   50
#define LPW   56
#define LPAD  4

// ---------------------------------------------------------------------------
// conv: grid (NIMG, CS). Block (bi, s) computes the full 96x96 image for
// out-channel i, batch b over channels [s*NC,(s+1)*NC), boundary-corrected,
// into part[s][bi][IMG]. x is staged per-channel into a zero-haloed LDS tile
// (double-buffered; padding comes free from the halo). Weight fold in-block.
// ---------------------------------------------------------------------------
template <int CS>
__global__ __launch_bounds__(256, 2) void conv_kernel(
        const float* __restrict__ x, const float* __restrict__ Wt,
        float* __restrict__ part) {
    constexpr int NC = CIN / CS;
    const int bi = blockIdx.x, s = blockIdx.y;
    const int b = bi >> 6, i = bi & 63, c0 = s * NC;
    const int tid = threadIdx.x;
    const int ty = tid >> 4, tx = tid & 15;

    __shared__ __align__(16) float sX[2][LPH * LPW];   // 22.4 KB
    __shared__ __align__(16) float sF[NC * 16];        // folded interior weights
    __shared__ float sW[NC * 16];                      // raw weights
    __shared__ float sR[NC * 16];                      // per-class reciprocals
    __shared__ float sFix[384];

    // ---- zero both LDS tiles (halo stays zero forever) + weight fold ----
    {
        const float4 z = make_float4(0.f, 0.f, 0.f, 0.f);
        float4* p0 = (float4*)&sX[0][0];
        for (int e = tid; e < 2 * LPH * LPW / 4; e += 256) p0[e] = z;
    }
    for (int e = tid; e < NC * 16; e += 256) {
        const int c = e >> 4, j = e & 15;
        const float* wp = Wt + ((size_t)(c0 + c) * NI + i) * 16;
        sW[e] = wp[j];
        const int py = (j >> 3) & 1, px = (j >> 2) & 1, a = (j >> 1) & 1, bb = j & 1;
        const int kh = py ? (a ? 2 : 0) : (a ? 3 : 1);
        const int kw = px ? (bb ? 2 : 0) : (bb ? 3 : 1);
        const int r0 = py ? 0 : 1, r1 = py ? 2 : 3;
        const int q0 = px ? 0 : 1, q1 = px ? 2 : 3;
        const float den = wp[r0 * 4 + q0] + wp[r0 * 4 + q1]
                        + wp[r1 * 4 + q0] + wp[r1 * 4 + q1];
        sF[e] = wp[kh * 4 + kw] / (den + EPSN);
        const int cy = j >> 2, cx = j & 3;
        const int THn[4] = {1, 2, 2, 1};
        const int THv[4][2] = {{1, 1}, {0, 2}, {1, 3}, {2, 2}};
        float den2 = 0.f;
        for (int aa = 0; aa < THn[cy]; ++aa)
            for (int bb2 = 0; bb2 < THn[cx]; ++bb2)
                den2 += wp[THv[cy][aa] * 4 + THv[cx][bb2]];
        sR[e] = 1.f / (den2 + EPSN);
    }

    // ---- staging geometry: 576 float4 per channel; thread handles e, e+256,
    //      and (tid<64) e+512.  float4 g -> row h=g/12, 4 cols starting 4*(g%12).
    int ldsOff[3];
#pragma unroll
    for (int k = 0; k < 3; ++k) {
        const int e = tid + 256 * k;
        const int h = e / 12, w4 = e - 12 * h;
        ldsOff[k] = (h + 1) * LPW + LPAD + 4 * w4;
    }
    const float4* xg = (const float4*)x + (size_t)(b * CIN + c0) * 576;

    // ---- boundary-pixel geometry (constant across channels) ----
    // p0 = tid (always < 380), p1 = tid + 256 (valid iff tid < 124)
    int q0A0, q0A1, q0B0, q0B1, w00, w01, w02, w03, cls0;
    int q1A0, q1A1, q1B0, q1B1, w10, w11, w12, w13, cls1;
#pragma unroll
    for (int k = 0; k < 2; ++k) {
        const int p = tid + 256 * k;
        if (k == 1 && p >= 380) break;
        int y, xo;
        if (p < 96)       { y = 0;            xo = p; }
        else if (p < 192) { y = 95;           xo = p - 96; }
        else if (p < 286) { y = p - 192 + 1;  xo = 0; }
        else              { y = p - 286 + 1;  xo = 95; }
        const int hA = (y + 1) >> 1, hB = hA - 1;
        const int khA = (y & 1) ? 0 : 1, khB = khA + 2;
        const int wA = (xo + 1) >> 1, wB = wA - 1;
        const int kwA = (xo & 1) ? 0 : 1, kwB = kwA + 2;
        const int cy = (y == 0) ? 0 : (y == 95) ? 3 : ((y & 1) ? 1 : 2);
        const int cx = (xo == 0) ? 0 : (xo == 95) ? 3 : ((xo & 1) ? 1 : 2);
        const int rA = (hA + 1) * LPW, rB = (hB + 1) * LPW;
        if (k == 0) {
            q0A0 = rA + LPAD + wA; q0A1 = rA + LPAD + wB;
            q0B0 = rB + LPAD + wA; q0B1 = rB + LPAD + wB;
            w00 = khA * 4 + kwA; w01 = khA * 4 + kwB;
            w02 = khB * 4 + kwA; w03 = khB * 4 + kwB;
            cls0 = cy * 4 + cx;
        } else {
            q1A0 = rA + LPAD + wA; q1A1 = rA + LPAD + wB;
            q1B0 = rB + LPAD + wA; q1B1 = rB + LPAD + wB;
            w10 = khA * 4 + kwA; w11 = khA * 4 + kwB;
            w12 = khB * 4 + kwA; w13 = khB * 4 + kwB;
            cls1 = cy * 4 + cx;
        }
    }

    __syncthreads();   // zeroing done before first staging write

    // ---- stage channel 0 into buffer 0 ----
    {
        float4 a0 = xg[tid], a1 = xg[tid + 256], a2;
        if (tid < 64) a2 = xg[tid + 512];
        float* dst = &sX[0][0];
        *(float4*)(dst + ldsOff[0]) = a0;
        *(float4*)(dst + ldsOff[1]) = a1;
        if (tid < 64) *(float4*)(dst + ldsOff[2]) = a2;
    }
    __syncthreads();

    float acc[6][6];
#pragma unroll
    for (int r = 0; r < 6; ++r)
#pragma unroll
        for (int j = 0; j < 6; ++j) acc[r][j] = 0.f;
    float fixAcc0 = 0.f, fixAcc1 = 0.f;

    const int patchBase = (3 * ty) * LPW + 3 * tx + (LPAD - 1);

#pragma unroll 2
    for (int c = 0; c < NC; ++c) {
        // prefetch next channel into registers
        float4 a0, a1, a2;
        if (c + 1 < NC) {
            const float4* xn = xg + (size_t)(c + 1) * 576;
            a0 = xn[tid]; a1 = xn[tid + 256];
            if (tid < 64) a2 = xn[tid + 512];
        }

        const float* __restrict__ xs = &sX[c & 1][0];

        float g[16];
        {
            const float4* gf = (const float4*)&sF[c * 16];
#pragma unroll
            for (int q = 0; q < 4; ++q) {
                const float4 t = gf[q];
                g[4 * q] = t.x; g[4 * q + 1] = t.y;
                g[4 * q + 2] = t.z; g[4 * q + 3] = t.w;
            }
        }

        float xv[5][5];
#pragma unroll
        for (int rr = 0; rr < 5; ++rr)
#pragma unroll
            for (int cc = 0; cc < 5; ++cc)
                xv[rr][cc] = xs[patchBase + rr * LPW + cc];

#pragma unroll
        for (int r = 0; r < 6; ++r) {
            const int rhi = (r + 3) >> 1, rlo = rhi - 1, py = r & 1;
#pragma unroll
            for (int j = 0; j < 6; ++j) {
                const int chi = (j + 3) >> 1, clo = chi - 1, px = j & 1;
                const float* gg = &g[py * 8 + px * 4];
                acc[r][j] += xv[rhi][chi] * gg[0] + xv[rhi][clo] * gg[1]
                           + xv[rlo][chi] * gg[2] + xv[rlo][clo] * gg[3];
            }
        }

        // boundary contribution of this channel (halo zeros cover OOB taps)
        {
            const float* wc = &sW[c * 16];
            const float num0 = xs[q0A0] * wc[w00] + xs[q0A1] * wc[w01]
                             + xs[q0B0] * wc[w02] + xs[q0B1] * wc[w03];
            fixAcc0 += num0 * sR[c * 16 + cls0];
            if (tid < 124) {
                const float num1 = xs[q1A0] * wc[w10] + xs[q1A1] * wc[w11]
                                 + xs[q1B0] * wc[w12] + xs[q1B1] * wc[w13];
                fixAcc1 += num1 * sR[c * 16 + cls1];
            }
        }

        // commit prefetched channel to the other buffer
        if (c + 1 < NC) {
            float* dst = &sX[(c + 1) & 1][0];
            *(float4*)(dst + ldsOff[0]) = a0;
            *(float4*)(dst + ldsOff[1]) = a1;
            if (tid < 64) *(float4*)(dst + ldsOff[2]) = a2;
        }
        __syncthreads();
    }

    // publish boundary sums, replace owners' boundary pixels
    sFix[tid] = fixAcc0;
    if (tid < 124) sFix[tid + 256] = fixAcc1;
    __syncthreads();

#pragma unroll
    for (int r = 0; r < 6; ++r)
#pragma unroll
        for (int j = 0; j < 6; ++j) {
            const int y = 6 * ty + r, xo = 6 * tx + j;
            if (y == 0)        acc[r][j] = sFix[xo];
            else if (y == 95)  acc[r][j] = sFix[96 + xo];
            else if (xo == 0)  acc[r][j] = sFix[192 + y - 1];
            else if (xo == 95) acc[r][j] = sFix[286 + y - 1];
        }

    float* pp = part + ((size_t)s * NIMG + bi) * IMG + (6 * ty) * WO + 6 * tx;
#pragma unroll
    for (int r = 0; r < 6; ++r)
#pragma unroll
        for (int jj = 0; jj < 3; ++jj) {
            float2 v;
            v.x = acc[r][2 * jj];
            v.y = acc[r][2 * jj + 1];
            *(float2*)(pp + r * WO + 2 * jj) = v;
        }
}

// ---------------------------------------------------------------------------
// epilogue: grid NIMG x 768 threads. Sum CS partials (float4), +bias,
// block-wide stats, normalize, write out. In-place safe for CS==1.
// ---------------------------------------------------------------------------
template <int CS>
__global__ __launch_bounds__(768) void epilogue_kernel(
        const float* __restrict__ part, const float* __restrict__ bias,
        float* __restrict__ out) {
    const int bi = blockIdx.x;
    const int tid = threadIdx.x;
    const float bv = bias[bi & 63];
    const float4* pb = (const float4*)part + (size_t)bi * (IMG / 4);
    const size_t stride4 = (size_t)NIMG * (IMG / 4);

    float4 v[3];
    float s1 = 0.f, s2 = 0.f;
#pragma unroll
    for (int k = 0; k < 3; ++k) {
        const int idx = k * 768 + tid;
        float4 t = pb[idx];
#pragma unroll
        for (int s = 1; s < CS; ++s) {
            const float4 q = pb[s * stride4 + idx];
            t.x += q.x; t.y += q.y; t.z += q.z; t.w += q.w;
        }
        t.x += bv; t.y += bv; t.z += bv; t.w += bv;
        v[k] = t;
        s1 += t.x + t.y + t.z + t.w;
        s2 += t.x * t.x + t.y * t.y + t.z * t.z + t.w * t.w;
    }

    __shared__ float red[24];
    __shared__ float stat[2];
#pragma unroll
    for (int off = 32; off > 0; off >>= 1) {
        s1 += __shfl_down(s1, off, 64);
        s2 += __shfl_down(s2, off, 64);
    }
    const int w = tid >> 6;
    if ((tid & 63) == 0) { red[w] = s1; red[12 + w] = s2; }
    __syncthreads();
    if (tid == 0) {
        float t1 = 0.f, t2 = 0.f;
#pragma unroll
        for (int k = 0; k < 12; ++k) { t1 += red[k]; t2 += red[12 + k]; }
        const float mean = t1 * (1.f / 9216.f);
        const float m2 = t2 * (1.f / 9216.f);
        stat[0] = mean;
        stat[1] = rsqrtf(m2 - mean * mean + IN_EPS);
    }
    __syncthreads();
    const float mean = stat[0], inv = stat[1];

    float4* ob = (float4*)out + (size_t)bi * (IMG / 4);
#pragma unroll
    for (int k = 0; k < 3; ++k) {
        const int idx = k * 768 + tid;
        float4 t = v[k];
        t.x = (t.x - mean) * inv; t.y = (t.y - mean) * inv;
        t.z = (t.z - mean) * inv; t.w = (t.w - mean) * inv;
        ob[idx] = t;
    }
}

extern "C" void kernel_launch(void* const* d_in, const int* in_sizes, int n_in,
                              void* d_out, int out_size, void* d_ws, size_t ws_size,
                              hipStream_t stream) {
    const float* x    = (const float*)d_in[0];
    const float* Wt   = (const float*)d_in[1];
    const float* bias = (const float*)d_in[2];
    float* out = (float*)d_out;
    float* ws  = (float*)d_ws;

    const size_t need4 = (size_t)4 * NIMG * IMG * 4;
    if (ws_size >= need4) {
        conv_kernel<4><<<dim3(NIMG, 4), 256, 0, stream>>>(x, Wt, ws);
        epilogue_kernel<4><<<NIMG, 768, 0, stream>>>(ws, bias, out);
    } else {
        // fallback: conv writes the corrected pre-bias image straight to out,
        // epilogue normalizes in place; needs no workspace.
        conv_kernel<1><<<dim3(NIMG, 1), 256, 0, stream>>>(x, Wt, out);
        epilogue_kernel<1><<<NIMG, 768, 0, stream>>>(out, bias, out);
    }
}